// Round 6
// baseline (497.407 us; speedup 1.0000x reference)
//
#include <hip/hip_runtime.h>

// RAFilter: I_RA[t] = a*I_RA[t-1] + c*|I[t]-I[t-1]|, I[-1]=0, I_RA[-1]=0
// a = 1 - DT/TAU = 0.99666667, c = K3/TAU = 0.06666667 (DT cancels).
// Shapes (B=8, T=4096, N=2048) fp32, time-stride = N floats (8KB).
//
// Two-kernel segmented scan, float4-wide lanes (clang ext_vector so
// __builtin_nontemporal_* accepts it):
//  - quad-chain q in [0,4096): 4 adjacent n. Wave-load = 1KB contiguous;
//    block of 8 same-seg adjacent cols covers 8KB contiguous per t-step.
//  - SEG=64 segments of L=64 steps.
//  - passA: segment end-state E[seg][q] -> ws (reads 63/64 of input).
//  - passB: carry = Horner over E (A=a^64), exact replay + store out.
// HBM floor ~81us; passB input re-read largely L3-resident (FETCH=254MB in
// the fused round-4 version).

typedef float f4 __attribute__((ext_vector_type(4)));

constexpr int Bb   = 8;
constexpr int Tn   = 4096;
constexpr int Nn   = 2048;
constexpr int NQ   = Nn / 4;        // 512 f4 per (b,t) row
constexpr int QTOT = Bb * NQ;       // 4096 quad-chains
constexpr int COLS = QTOT / 64;     // 64 wave-columns
constexpr int SEG  = 64;
constexpr int L    = Tn / SEG;      // 64 steps per segment
constexpr int U    = 8;             // f4 loads per chunk
constexpr int WPB  = 8;             // waves per block (512 threads)

__device__ __forceinline__ void step4(f4& st, f4& prev, const f4 x,
                                      float a, float c) {
#pragma unroll
    for (int i = 0; i < 4; ++i)
        st[i] = fmaf(a, st[i], c * fabsf(x[i] - prev[i]));
    prev = x;
}

__global__ __launch_bounds__(64 * WPB) void ra_passA(
    const f4* __restrict__ in4, f4* __restrict__ E4) {
    const int lane = threadIdx.x & 63;
    const int wid  = threadIdx.x >> 6;
    const int seg  = blockIdx.x / (COLS / WPB);          // 0..62
    const int col  = (blockIdx.x % (COLS / WPB)) * WPB + wid;
    const int q    = col * 64 + lane;                    // quad-chain id
    const int b    = q >> 9;                             // q / 512
    const int nq   = q & (NQ - 1);
    const int t0   = seg * L;

    const float a = 0.99666666666666667f;
    const float c = 0.06666666666666667f;

    const f4* p = in4 + ((size_t)b * Tn + t0) * NQ + nq;

    f4 prev = (t0 > 0) ? __builtin_nontemporal_load(p - NQ) : (f4)(0.f);
    f4 st = (f4)(0.f);

    f4 xa[U], xb[U];
#pragma unroll
    for (int u = 0; u < U; ++u)
        xa[u] = __builtin_nontemporal_load(p + (size_t)u * NQ);

    for (int tt = 0; tt < L; tt += 2 * U) {
#pragma unroll
        for (int u = 0; u < U; ++u)
            xb[u] = __builtin_nontemporal_load(p + (size_t)(tt + U + u) * NQ);
#pragma unroll
        for (int u = 0; u < U; ++u) step4(st, prev, xa[u], a, c);
        if (tt + 2 * U < L) {
#pragma unroll
            for (int u = 0; u < U; ++u)
                xa[u] = __builtin_nontemporal_load(p + (size_t)(tt + 2 * U + u) * NQ);
        }
#pragma unroll
        for (int u = 0; u < U; ++u) step4(st, prev, xb[u], a, c);
    }

    E4[(size_t)seg * QTOT + q] = st;
}

__global__ __launch_bounds__(64 * WPB) void ra_passB(
    const f4* __restrict__ in4, const f4* __restrict__ E4,
    f4* __restrict__ out4) {
    const int lane = threadIdx.x & 63;
    const int wid  = threadIdx.x >> 6;
    const int seg  = blockIdx.x / (COLS / WPB);          // 0..63
    const int col  = (blockIdx.x % (COLS / WPB)) * WPB + wid;
    const int q    = col * 64 + lane;
    const int b    = q >> 9;
    const int nq   = q & (NQ - 1);
    const int t0   = seg * L;

    const float a = 0.99666666666666667f;
    const float c = 0.06666666666666667f;
    float A = a;                                          // A = a^64
#pragma unroll
    for (int i = 0; i < 6; ++i) A *= A;

    // carry = sum_{j<seg} E_j * A^(seg-1-j)  (Horner; E is 4MB, L2-resident)
    f4 carry = (f4)(0.f);
    for (int j = 0; j < seg; ++j) {
        f4 e = E4[(size_t)j * QTOT + q];
#pragma unroll
        for (int i = 0; i < 4; ++i) carry[i] = fmaf(A, carry[i], e[i]);
    }

    const f4* p = in4  + ((size_t)b * Tn + t0) * NQ + nq;
    f4*       o = out4 + ((size_t)b * Tn + t0) * NQ + nq;

    f4 prev = (t0 > 0) ? __builtin_nontemporal_load(p - NQ) : (f4)(0.f);
    f4 st = carry;

    f4 xa[U], xb[U];
#pragma unroll
    for (int u = 0; u < U; ++u)
        xa[u] = __builtin_nontemporal_load(p + (size_t)u * NQ);

    for (int tt = 0; tt < L; tt += 2 * U) {
#pragma unroll
        for (int u = 0; u < U; ++u)
            xb[u] = __builtin_nontemporal_load(p + (size_t)(tt + U + u) * NQ);
#pragma unroll
        for (int u = 0; u < U; ++u) {
            step4(st, prev, xa[u], a, c);
            xa[u] = st;
        }
#pragma unroll
        for (int u = 0; u < U; ++u)
            __builtin_nontemporal_store(xa[u], o + (size_t)(tt + u) * NQ);
        if (tt + 2 * U < L) {
#pragma unroll
            for (int u = 0; u < U; ++u)
                xa[u] = __builtin_nontemporal_load(p + (size_t)(tt + 2 * U + u) * NQ);
        }
#pragma unroll
        for (int u = 0; u < U; ++u) {
            step4(st, prev, xb[u], a, c);
            xb[u] = st;
        }
#pragma unroll
        for (int u = 0; u < U; ++u)
            __builtin_nontemporal_store(xb[u], o + (size_t)(tt + U + u) * NQ);
    }
}

extern "C" void kernel_launch(void* const* d_in, const int* in_sizes, int n_in,
                              void* d_out, int out_size, void* d_ws, size_t ws_size,
                              hipStream_t stream) {
    const f4* in4 = (const f4*)d_in[0];
    f4* out4 = (f4*)d_out;
    f4* E4 = (f4*)d_ws;             // 64 segs x 4096 quads x 16B = 4MB

    dim3 block(64 * WPB);
    dim3 gridA((SEG - 1) * (COLS / WPB));   // 63*8 = 504 blocks (seg 63 E unused)
    dim3 gridB(SEG * (COLS / WPB));         // 64*8 = 512 blocks
    hipLaunchKernelGGL(ra_passA, gridA, block, 0, stream, in4, E4);
    hipLaunchKernelGGL(ra_passB, gridB, block, 0, stream, in4, E4, out4);
}